// Round 8
// baseline (226.168 us; speedup 1.0000x reference)
//
#include <hip/hip_runtime.h>
#include <cmath>

#define NB    64
#define TENC  1024
#define DENC  512
#define QDIM  1024
#define HDIM  256
#define NM    5
#define EPSF  1e-5f
#define DCH   128                 // d-columns per context block
#define NDCH  (DENC / DCH)        // 4 d-chunks -> 64*4 = 256 blocks = 1/CU
#define NTHR  1024                // R8: 16 waves/CU (was 8)

// ---------------------------------------------------------------------------
// Single fused kernel. Grid = NB * NDCH = 256 blocks, 1024 threads (16 waves/CU).
// R8 experiment: the kernel has been pinned at ~76us across three structural
// changes (R5 lockstep-break, R7 deep prefetch). Two surviving theories:
//   (1) wave starvation (8 waves/CU too few) -> this round doubles waves/CU;
//   (2) harness-induced memory state (512MB poison fill evicts LLC + drains
//       dirty lines into my kernel's window) -> nothing in-kernel helps.
// 1024 threads distinguishes them: (1) predicts ~2x faster stream, (2) neutral.
// Structure otherwise identical: group-of-8 prefetch, per-batch t-rotation,
// no fences/atomics (R3 lesson).
// ---------------------------------------------------------------------------
__global__ __launch_bounds__(NTHR) void mol_fused(
    const float* __restrict__ q,        // B x 1024
    const float* __restrict__ W1,       // 1024 x 256 (row-major)
    const float* __restrict__ b1,       // 256
    const float* __restrict__ W2,       // 256 x 15
    const float* __restrict__ b2,       // 15
    const float* __restrict__ mu_prev,  // B x 5
    const float* __restrict__ memory,   // B x T x D
    const unsigned char* __restrict__ mask, // B x T
    float* __restrict__ alpha_out,      // B x T (in d_out)
    float* __restrict__ context)        // B x DENC (in d_out)
{
    __shared__ float  q_lds[QDIM];         // 4 KB
    __shared__ float4 part16[16][64];      // 16 KB (split-K partials for h)
    __shared__ float  h_lds[HDIM];         // 1 KB
    __shared__ float  p_part[15][16];      // split-K partials for params
    __shared__ float  p_lds[16];
    __shared__ float  stats[16];           // w[5], sigma[5], mu[5]
    __shared__ float  a_lds[TENC];         // 4 KB
    __shared__ float4 red[32 * 32];        // 16 KB

    const int b   = blockIdx.x >> 2;       // / NDCH
    const int dch = blockIdx.x & (NDCH - 1);
    const int tid = threadIdx.x;
    const int d0  = dch * DCH;

    // ---- stage q row (4 KB), float4-coalesced ----
    if (tid < 256)
        ((float4*)q_lds)[tid] = ((const float4*)(q + (size_t)b * QDIM))[tid];
    __syncthreads();

    // ---- h = relu(q @ W1 + b1): (g = k-group 0..15, c = output float4 0..63)
    //      64 k-iters/thread, group-of-8 prefetch ----
    {
        const int g = tid >> 6;
        const int c = tid & 63;
        const float4* W1v = (const float4*)W1 + c;   // [k][64] float4, col c
        float4 acc = make_float4(0.f, 0.f, 0.f, 0.f);
        const int k0 = g << 6;                       // 64 k-rows per group
        for (int kk = 0; kk < 64; kk += 8) {
            float4 wv[8];
            float  qk[8];
            #pragma unroll
            for (int j = 0; j < 8; ++j) {
                qk[j] = q_lds[k0 + kk + j];                    // wave-broadcast
                wv[j] = W1v[(size_t)(k0 + kk + j) * 64];       // back-to-back issue
            }
            #pragma unroll
            for (int j = 0; j < 8; ++j) {
                acc.x = fmaf(qk[j], wv[j].x, acc.x);
                acc.y = fmaf(qk[j], wv[j].y, acc.y);
                acc.z = fmaf(qk[j], wv[j].z, acc.z);
                acc.w = fmaf(qk[j], wv[j].w, acc.w);
            }
        }
        part16[g][c] = acc;
    }
    __syncthreads();

    if (tid < 64) {
        float4 s = part16[0][tid];
        #pragma unroll
        for (int g = 1; g < 16; ++g) {
            const float4 v = part16[g][tid];
            s.x += v.x; s.y += v.y; s.z += v.z; s.w += v.w;
        }
        const float4 bb = ((const float4*)b1)[tid];
        float4 h;
        h.x = fmaxf(s.x + bb.x, 0.f);
        h.y = fmaxf(s.y + bb.y, 0.f);
        h.z = fmaxf(s.z + bb.z, 0.f);
        h.w = fmaxf(s.w + bb.w, 0.f);
        ((float4*)h_lds)[tid] = h;
    }
    __syncthreads();

    // ---- params = h @ W2 + b2 : 15 outputs x 16 k-groups of 16 ----
    if (tid < 240) {
        const int o  = tid >> 4;        // output 0..14
        const int kg = tid & 15;        // k-group 0..15
        float acc = 0.f;
        #pragma unroll
        for (int i = 0; i < 16; ++i) {
            const int k = kg * 16 + i;
            acc = fmaf(h_lds[k], W2[k * 15 + o], acc);
        }
        p_part[o][kg] = acc;
    }
    __syncthreads();
    if (tid < 15) {
        float acc = b2[tid];
        #pragma unroll
        for (int kg = 0; kg < 16; ++kg) acc += p_part[tid][kg];
        p_lds[tid] = acc;
    }
    __syncthreads();

    // ---- stats ----
    if (tid == 0) {
        float mx = p_lds[0];
        #pragma unroll
        for (int m = 1; m < NM; ++m) mx = fmaxf(mx, p_lds[m]);
        float e[NM], se = 0.f;
        #pragma unroll
        for (int m = 0; m < NM; ++m) { e[m] = expf(p_lds[m] - mx); se += e[m]; }
        const float inv = 1.f / se;
        #pragma unroll
        for (int m = 0; m < NM; ++m) stats[m] = e[m] * inv + EPSF;
        #pragma unroll
        for (int m = 0; m < NM; ++m) {      // sigma = softplus + eps (stable)
            const float x = p_lds[NM + m];
            stats[NM + m] = fmaxf(x, 0.f) + log1pf(expf(-fabsf(x))) + EPSF;
        }
        #pragma unroll
        for (int m = 0; m < NM; ++m) {      // mu = mu_prev + softplus(Delta)
            const float x = p_lds[2 * NM + m];
            stats[2 * NM + m] = mu_prev[b * NM + m] + fmaxf(x, 0.f) + log1pf(expf(-fabsf(x)));
        }
    }
    __syncthreads();

    // ---- alpha: 1 t-value per thread ----
    {
        const int t = tid;
        const float jA = (float)t + 0.5f;
        const float jB = (float)t + 1.5f;
        float FA = 0.f, FB = 0.f;
        #pragma unroll
        for (int m = 0; m < NM; ++m) {
            const float w   = stats[m];
            const float isg = 1.f / stats[NM + m];
            const float mu  = stats[2 * NM + m];
            const float sA = 1.f / (1.f + expf(-(mu - jA) * isg));   // sigmoid
            const float sB = 1.f / (1.f + expf(-(mu - jB) * isg));
            FA += w / (1.f + sA);
            FB += w / (1.f + sB);
        }
        float a = FB - FA;
        if (a == 0.f) a = EPSF;                  // where(alpha==0, EPS)
        if (mask[(size_t)b * TENC + t]) a = 0.f; // where(mask, 0)
        a_lds[t] = a;
        if (dch == 0) alpha_out[(size_t)b * TENC + t] = a;  // coalesced
    }
    __syncthreads();

    // ---- stream the 512 KB slice: (tp = t-phase 0..31, dc = float4 col 0..31)
    //      32 t-steps/thread, group-of-8 prefetch (8 KB/wave in flight),
    //      16 waves/CU. t rotated by b*16 (R6, kept). ----
    const int dc = tid & 31;
    const int tp = tid >> 5;
    const int tshift = b << 4;                   // per-batch phase offset
    const float4* mem4 = (const float4*)(memory + (size_t)b * TENC * DENC)
                         + (d0 >> 2) + dc;

    float4 acc = make_float4(0.f, 0.f, 0.f, 0.f);
    for (int i = 0; i < 32; i += 8) {            // 32 t-steps per thread
        float4 mv[8];
        float  av[8];
        #pragma unroll
        for (int j = 0; j < 8; ++j) {
            const int t = ((i + j) * 32 + tp + tshift) & (TENC - 1);
            mv[j] = mem4[(size_t)t * (DENC / 4)];   // 8 loads issued together
            av[j] = a_lds[t];
        }
        #pragma unroll
        for (int j = 0; j < 8; ++j) {
            acc.x = fmaf(av[j], mv[j].x, acc.x);
            acc.y = fmaf(av[j], mv[j].y, acc.y);
            acc.z = fmaf(av[j], mv[j].z, acc.z);
            acc.w = fmaf(av[j], mv[j].w, acc.w);
        }
    }

    // ---- 32-way reduction per d-column, one float4 store per column ----
    red[tp * 32 + dc] = acc;
    __syncthreads();
    if (tid < 32) {
        float4 r = red[tid];
        #pragma unroll
        for (int s = 1; s < 32; ++s) {
            const float4 v = red[s * 32 + tid];
            r.x += v.x; r.y += v.y; r.z += v.z; r.w += v.w;
        }
        ((float4*)(context + (size_t)b * DENC + d0))[tid] = r;
    }
}

extern "C" void kernel_launch(void* const* d_in, const int* in_sizes, int n_in,
                              void* d_out, int out_size, void* d_ws, size_t ws_size,
                              hipStream_t stream) {
    const float*         q       = (const float*)d_in[0];          // att_rnn_h (64,1024)
    const float*         memory  = (const float*)d_in[1];          // (64,1024,512)
    const unsigned char* mask    = (const unsigned char*)d_in[2];  // bool (64,1024)
    const float*         mu_prev = (const float*)d_in[3];          // (64,5)
    const float*         W1      = (const float*)d_in[4];          // (1024,256)
    const float*         b1      = (const float*)d_in[5];          // (256,)
    const float*         W2      = (const float*)d_in[6];          // (256,15)
    const float*         b2      = (const float*)d_in[7];          // (15,)

    float* out   = (float*)d_out;
    float* ctx   = out;                  // context: first 64*512 floats
    float* alpha = out + NB * DENC;      // alpha_t: next 64*1024 floats

    mol_fused<<<NB * NDCH, NTHR, 0, stream>>>(q, W1, b1, W2, b2, mu_prev,
                                              memory, mask, alpha, ctx);
}